// Round 2
// baseline (1069.152 us; speedup 1.0000x reference)
//
#include <hip/hip_runtime.h>
#include <hip/hip_bf16.h>

// Problem constants
#define S_LEN 512
#define BATCH 64
#define EMB   300
#define HD    128
#define G4    512      // 4*HD
#define NT    9
#define NCH   64       // CRF scan chunks
#define CHL   8        // chunk length (last chunk = 7)

typedef unsigned short u16;
typedef __attribute__((ext_vector_type(8))) short short8;
typedef __attribute__((ext_vector_type(4))) float f32x4;

__device__ __forceinline__ float bf2f(u16 u) {
  union { unsigned int i; float f; } v; v.i = ((unsigned int)u) << 16; return v.f;
}
__device__ __forceinline__ u16 f2bf(float f) {
  union { float f; unsigned int i; } v; v.f = f;
  unsigned int u = v.i + 0x7fffu + ((v.i >> 16) & 1u);   // RNE, finite inputs
  return (u16)(u >> 16);
}
__device__ __forceinline__ float sigm(float x) { return 1.0f / (1.0f + __expf(-x)); }
__device__ __forceinline__ float tanh_(float x) {
  float e = __expf(-2.0f * fabsf(x));
  float t = (1.0f - e) / (1.0f + e);
  return x >= 0.0f ? t : -t;
}

// ---------------------------------------------------------------------------
// K1: embedding gather + input projection GEMM (bf16 MFMA).  (unchanged)
// xproj[m][n], m = s*64+b, n in [0,1024): n<512 fwd, else bwd; i,f,g,o blocks.
// ---------------------------------------------------------------------------
__global__ __launch_bounds__(256) void k_xproj(
    const int* __restrict__ words, const float* __restrict__ emb,
    const float* __restrict__ Wf, const float* __restrict__ Wb,
    const float* __restrict__ bihf, const float* __restrict__ bhhf,
    const float* __restrict__ bihb, const float* __restrict__ bhhb,
    u16* __restrict__ xproj)
{
  __shared__ u16  As[128 * 40];
  __shared__ u16  Bs[128 * 40];
  __shared__ int  wlds[128];
  __shared__ float blds[128];
  const int tid = threadIdx.x;
  const int m0 = blockIdx.x * 128;
  const int n0 = blockIdx.y * 128;
  if (tid < 128) {
    int m = m0 + tid;
    wlds[tid] = words[(m & 63) * S_LEN + (m >> 6)];
    int n = n0 + tid;
    blds[tid] = (n < G4) ? (bihf[n] + bhhf[n]) : (bihb[n - G4] + bhhb[n - G4]);
  }
  __syncthreads();

  const int lane = tid & 63;
  const int w = tid >> 6;
  const int wr = w >> 1, wc = w & 1;
  const int l15 = lane & 15, l4 = lane >> 4;

  f32x4 acc[4][4];
#pragma unroll
  for (int a = 0; a < 4; ++a)
#pragma unroll
    for (int b = 0; b < 4; ++b) acc[a][b] = (f32x4){0.f, 0.f, 0.f, 0.f};

  const int rr = tid >> 3;
  const int kk = (tid & 7) * 4;

  for (int kt = 0; kt < 10; ++kt) {
    const int k0 = kt * 32;
    if (kt) __syncthreads();
#pragma unroll
    for (int q = 0; q < 4; ++q) {
      int r = rr + q * 32;
      {
        const float* src = emb + (long)wlds[r] * EMB + (k0 + kk);
        float4 v;
        if (k0 + kk + 3 < EMB) v = *(const float4*)src;
        else {
          v.x = (k0 + kk + 0 < EMB) ? src[0] : 0.f;
          v.y = (k0 + kk + 1 < EMB) ? src[1] : 0.f;
          v.z = (k0 + kk + 2 < EMB) ? src[2] : 0.f;
          v.w = (k0 + kk + 3 < EMB) ? src[3] : 0.f;
        }
        ushort4 o = { f2bf(v.x), f2bf(v.y), f2bf(v.z), f2bf(v.w) };
        *(ushort4*)&As[r * 40 + kk] = o;
      }
      {
        int n = n0 + r;
        const float* src = (n < G4) ? (Wf + (long)n * EMB + (k0 + kk))
                                    : (Wb + (long)(n - G4) * EMB + (k0 + kk));
        float4 v;
        if (k0 + kk + 3 < EMB) v = *(const float4*)src;
        else {
          v.x = (k0 + kk + 0 < EMB) ? src[0] : 0.f;
          v.y = (k0 + kk + 1 < EMB) ? src[1] : 0.f;
          v.z = (k0 + kk + 2 < EMB) ? src[2] : 0.f;
          v.w = (k0 + kk + 3 < EMB) ? src[3] : 0.f;
        }
        ushort4 o = { f2bf(v.x), f2bf(v.y), f2bf(v.z), f2bf(v.w) };
        *(ushort4*)&Bs[r * 40 + kk] = o;
      }
    }
    __syncthreads();

    short8 af[4], bfv[4];
#pragma unroll
    for (int mt = 0; mt < 4; ++mt)
      af[mt] = *(const short8*)&As[(wr * 64 + mt * 16 + l15) * 40 + l4 * 8];
#pragma unroll
    for (int nt = 0; nt < 4; ++nt)
      bfv[nt] = *(const short8*)&Bs[(wc * 64 + nt * 16 + l15) * 40 + l4 * 8];
#pragma unroll
    for (int mt = 0; mt < 4; ++mt)
#pragma unroll
      for (int nt = 0; nt < 4; ++nt)
        acc[mt][nt] = __builtin_amdgcn_mfma_f32_16x16x32_bf16(af[mt], bfv[nt], acc[mt][nt], 0, 0, 0);
  }

#pragma unroll
  for (int nt = 0; nt < 4; ++nt) {
    int col = wc * 64 + nt * 16 + l15;
    float bias = blds[col];
    long n = n0 + col;
#pragma unroll
    for (int mt = 0; mt < 4; ++mt) {
#pragma unroll
      for (int r = 0; r < 4; ++r) {
        int m = m0 + wr * 64 + mt * 16 + l4 * 4 + r;
        xproj[(long)m * 1024 + n] = f2bf(acc[mt][nt][r] + bias);
      }
    }
  }
}

// ---------------------------------------------------------------------------
// K2: LSTM recurrence, gate-register-local layout.
// 8 blocks = 2 dirs x 4 groups of 16 batches, 512 threads (8 waves).
// Wave w owns j in [16w,16w+16) for ALL 4 gates:
//   A-tile g rows = Whh rows g*128 + w*16 + (0..15).
//   D frag: col=batch(l15), row-in-tile = l4*4+r  ->  j = w*16+l4*4+r.
// => (i,f,g,o)[j] land in one lane's acc[0..3][r]; activation register-local.
// Only h crosses waves: double-buffered XOR-swizzled 4KB LDS, 1 barrier/step.
// ---------------------------------------------------------------------------
__global__ __launch_bounds__(512) void k_lstm(
    const u16* __restrict__ xproj, const float* __restrict__ Whh_f,
    const float* __restrict__ Whh_b, u16* __restrict__ h_glob)
{
  __shared__ u16 hls[2][16 * HD];   // [buf][batch row (256B)][swizzled j*2]

  const int dir = blockIdx.x >> 2;
  const int b0  = (blockIdx.x & 3) * 16;
  const float* Whh = dir ? Whh_b : Whh_f;
  const int tid = threadIdx.x;
  const int lane = tid & 63, w = tid >> 6;
  const int l15 = lane & 15, l4 = lane >> 4;
  const int swz = (l15 & 7) << 4;

  // persistent A-fragments: afr[g][kt], rows g*128 + w*16 + l15
  short8 afr[4][4];
#pragma unroll
  for (int g = 0; g < 4; ++g)
#pragma unroll
    for (int kt = 0; kt < 4; ++kt) {
      const float* src = Whh + (long)(g * 128 + w * 16 + l15) * HD + kt * 32 + l4 * 8;
      float4 v0 = *(const float4*)src;
      float4 v1 = *(const float4*)(src + 4);
      short8 f;
      f[0] = (short)f2bf(v0.x); f[1] = (short)f2bf(v0.y);
      f[2] = (short)f2bf(v0.z); f[3] = (short)f2bf(v0.w);
      f[4] = (short)f2bf(v1.x); f[5] = (short)f2bf(v1.y);
      f[6] = (short)f2bf(v1.z); f[7] = (short)f2bf(v1.w);
      afr[g][kt] = f;
    }
  for (int i = tid; i < 16 * HD; i += 512) hls[0][i] = 0;

  const int bglob = b0 + l15;
  const int jbase = w * 16 + l4 * 4;              // this lane's first j
  const int wbyte = (jbase * 2) ^ swz;            // swizzled LDS byte col for h write
  float c[4] = {0.f, 0.f, 0.f, 0.f};

  // prefetch xproj for t=0
  ushort4 xpc[4], xpn[4];
  {
    const long xb = ((long)(dir ? (S_LEN - 1) : 0) * BATCH + bglob) * 1024 + (long)dir * G4;
#pragma unroll
    for (int g = 0; g < 4; ++g)
      xpc[g] = *(const ushort4*)&xproj[xb + g * 128 + jbase];
  }
  __syncthreads();

  for (int t = 0; t < S_LEN; ++t) {
    const int cur = t & 1;
    // prefetch next step's xproj (clamped; unused at t=511)
    {
      int tn = (t + 1 < S_LEN) ? t + 1 : t;
      int sn = dir ? (S_LEN - 1 - tn) : tn;
      const long xb = ((long)sn * BATCH + bglob) * 1024 + (long)dir * G4;
#pragma unroll
      for (int g = 0; g < 4; ++g)
        xpn[g] = *(const ushort4*)&xproj[xb + g * 128 + jbase];
    }

    // B-fragments: h_{t-1}, col = batch(l15), k = kt*32 + l4*8 + e
    short8 bfr[4];
#pragma unroll
    for (int kt = 0; kt < 4; ++kt) {
      int off = l15 * 256 + ((kt * 64 + l4 * 16) ^ swz);
      bfr[kt] = *(const short8*)((const char*)&hls[cur][0] + off);
    }
    f32x4 acc[4];
#pragma unroll
    for (int g = 0; g < 4; ++g) acc[g] = (f32x4){0.f, 0.f, 0.f, 0.f};
#pragma unroll
    for (int kt = 0; kt < 4; ++kt) {
      acc[0] = __builtin_amdgcn_mfma_f32_16x16x32_bf16(afr[0][kt], bfr[kt], acc[0], 0, 0, 0);
      acc[1] = __builtin_amdgcn_mfma_f32_16x16x32_bf16(afr[1][kt], bfr[kt], acc[1], 0, 0, 0);
      acc[2] = __builtin_amdgcn_mfma_f32_16x16x32_bf16(afr[2][kt], bfr[kt], acc[2], 0, 0, 0);
      acc[3] = __builtin_amdgcn_mfma_f32_16x16x32_bf16(afr[3][kt], bfr[kt], acc[3], 0, 0, 0);
    }

    // activation, fully register-local: acc[g][r] is gate g at j = jbase+r
    ushort4 hv;
    const u16* xi = (const u16*)&xpc[0];
    const u16* xf = (const u16*)&xpc[1];
    const u16* xg = (const u16*)&xpc[2];
    const u16* xo = (const u16*)&xpc[3];
    float hr[4];
#pragma unroll
    for (int r = 0; r < 4; ++r) {
      float gi = acc[0][r] + bf2f(xi[r]);
      float gf = acc[1][r] + bf2f(xf[r]);
      float gg = acc[2][r] + bf2f(xg[r]);
      float go = acc[3][r] + bf2f(xo[r]);
      float si = sigm(gi), sf = sigm(gf), tg = tanh_(gg), so = sigm(go);
      c[r] = sf * c[r] + si * tg;
      hr[r] = so * tanh_(c[r]);
    }
    hv.x = f2bf(hr[0]); hv.y = f2bf(hr[1]); hv.z = f2bf(hr[2]); hv.w = f2bf(hr[3]);

    // write h_t: LDS (next buffer) + global
    *(ushort4*)((char*)&hls[cur ^ 1][0] + l15 * 256 + wbyte) = hv;
    const int s = dir ? (S_LEN - 1 - t) : t;
    *(ushort4*)&h_glob[((long)((dir * S_LEN + s) * BATCH + bglob)) * HD + jbase] = hv;

#pragma unroll
    for (int g = 0; g < 4; ++g) xpc[g] = xpn[g];
    __syncthreads();
  }
}

// ---------------------------------------------------------------------------
// K3: em = [h_f|h_b] @ W_out^T + b_out   (unchanged)
// ---------------------------------------------------------------------------
__global__ __launch_bounds__(256) void k_em(
    const u16* __restrict__ h_glob, const float* __restrict__ W_out,
    const float* __restrict__ b_out, float* __restrict__ em)
{
  __shared__ float wl[NT * 256];
  __shared__ float bl[NT];
  const int tid = threadIdx.x;
  for (int i = tid; i < NT * 256; i += 256) wl[i] = W_out[i];
  if (tid < NT) bl[tid] = b_out[tid];
  __syncthreads();

  const int m = blockIdx.x * 256 + tid;
  const u16* hf = h_glob + (long)m * HD;
  const u16* hb = h_glob + (long)(S_LEN * BATCH + m) * HD;
  float acc[NT];
#pragma unroll
  for (int tg = 0; tg < NT; ++tg) acc[tg] = bl[tg];

#pragma unroll
  for (int ch = 0; ch < 16; ++ch) {
    short8 v = *(const short8*)(hf + ch * 8);
    float f[8];
#pragma unroll
    for (int e = 0; e < 8; ++e) f[e] = bf2f((u16)v[e]);
#pragma unroll
    for (int tg = 0; tg < NT; ++tg) {
      const float* wp = &wl[tg * 256 + ch * 8];
      acc[tg] += f[0]*wp[0] + f[1]*wp[1] + f[2]*wp[2] + f[3]*wp[3]
               + f[4]*wp[4] + f[5]*wp[5] + f[6]*wp[6] + f[7]*wp[7];
    }
  }
#pragma unroll
  for (int ch = 0; ch < 16; ++ch) {
    short8 v = *(const short8*)(hb + ch * 8);
    float f[8];
#pragma unroll
    for (int e = 0; e < 8; ++e) f[e] = bf2f((u16)v[e]);
#pragma unroll
    for (int tg = 0; tg < NT; ++tg) {
      const float* wp = &wl[tg * 256 + 128 + ch * 8];
      acc[tg] += f[0]*wp[0] + f[1]*wp[1] + f[2]*wp[2] + f[3]*wp[3]
               + f[4]*wp[4] + f[5]*wp[5] + f[6]*wp[6] + f[7]*wp[7];
    }
  }
  float* dst = em + (long)m * NT;
#pragma unroll
  for (int tg = 0; tg < NT; ++tg) dst[tg] = acc[tg];
}

// ---------------------------------------------------------------------------
// K4: CRF numerator (gold path score).  (unchanged)
// ---------------------------------------------------------------------------
__global__ __launch_bounds__(256) void k_score(
    const int* __restrict__ tags, const float* __restrict__ em,
    const float* __restrict__ start, const float* __restrict__ endt,
    const float* __restrict__ trans, float* __restrict__ score)
{
  __shared__ float red[256];
  const int b = blockIdx.x, tid = threadIdx.x;
  const int* tg = tags + (long)b * S_LEN;
  float p = 0.f;
  for (int t = tid; t < S_LEN; t += 256) {
    int cur = tg[t];
    if (t == 0) p += start[cur] + em[(long)b * NT + cur];
    else        p += trans[tg[t - 1] * NT + cur] + em[(long)(t * BATCH + b) * NT + cur];
  }
  if (tid == 0) p += endt[tg[S_LEN - 1]];
  red[tid] = p;
  __syncthreads();
  for (int stp = 128; stp; stp >>= 1) {
    if (tid < stp) red[tid] += red[tid + stp];
    __syncthreads();
  }
  if (tid == 0) score[b] = red[0];
}

// ---------------------------------------------------------------------------
// K5a: CRF log-semiring chunk transfer matrices (fully parallel).
// pair = (chunk c, batch b); 16 lanes per pair, lanes i<9 own row i of R.
// M_c = A_{t0} (x) A_{t0+1} (x) ... , A_t[i][j] = trans[i][j] + em[t][b][j].
// ---------------------------------------------------------------------------
__global__ __launch_bounds__(256) void k_chainA(
    const float* __restrict__ em, const float* __restrict__ trans,
    float* __restrict__ chainM)   // [NCH][BATCH][9][9]
{
  const int tid = threadIdx.x;
  const int pair = (blockIdx.x * 256 + tid) >> 4;   // 0..4095
  const int i = tid & 15;
  const int b = pair & 63;
  const int c = pair >> 6;
  if (i >= 9) return;

  float tr[9][9];
#pragma unroll
  for (int k = 0; k < 9; ++k)
#pragma unroll
    for (int j = 0; j < 9; ++j) tr[k][j] = trans[k * 9 + j];

  const int t0 = 1 + c * CHL;
  const int tend = (t0 + CHL < S_LEN) ? (t0 + CHL) : S_LEN;

  float R[9];
#pragma unroll
  for (int j = 0; j < 9; ++j) R[j] = tr[i][j] + em[((long)t0 * BATCH + b) * NT + j];

  for (int t = t0 + 1; t < tend; ++t) {
    float e[9];
#pragma unroll
    for (int j = 0; j < 9; ++j) e[j] = em[((long)t * BATCH + b) * NT + j];
    float Rn[9];
#pragma unroll
    for (int j = 0; j < 9; ++j) {
      float sv[9];
#pragma unroll
      for (int k = 0; k < 9; ++k) sv[k] = R[k] + tr[k][j];
      float mx = sv[0];
#pragma unroll
      for (int k = 1; k < 9; ++k) mx = fmaxf(mx, sv[k]);
      float sm = 0.f;
#pragma unroll
      for (int k = 0; k < 9; ++k) sm += __expf(sv[k] - mx);
      Rn[j] = mx + __logf(sm) + e[j];
    }
#pragma unroll
    for (int j = 0; j < 9; ++j) R[j] = Rn[j];
  }
#pragma unroll
  for (int j = 0; j < 9; ++j)
    chainM[((long)(c * BATCH + b) * 9 + i) * 9 + j] = R[j];
}

// ---------------------------------------------------------------------------
// K5b: sequential combine over 64 chunk matrices. 1 block, 576 thr = (b,j).
// ---------------------------------------------------------------------------
__global__ __launch_bounds__(576) void k_denomB(
    const float* __restrict__ em, const float* __restrict__ chainM,
    const float* __restrict__ start, const float* __restrict__ endt,
    float* __restrict__ denom)
{
  __shared__ float al[BATCH * 12];
  const int tid = threadIdx.x;
  const int b = tid / NT, j = tid % NT;
  al[b * 12 + j] = start[j] + em[(long)b * NT + j];
  __syncthreads();

  for (int c = 0; c < NCH; ++c) {
    const float* M = chainM + (long)(c * BATCH + b) * 81 + j;
    float sv[9];
#pragma unroll
    for (int i = 0; i < 9; ++i) sv[i] = al[b * 12 + i] + M[i * 9];
    float mx = sv[0];
#pragma unroll
    for (int i = 1; i < 9; ++i) mx = fmaxf(mx, sv[i]);
    float sm = 0.f;
#pragma unroll
    for (int i = 0; i < 9; ++i) sm += __expf(sv[i] - mx);
    float nv = mx + __logf(sm);
    __syncthreads();
    al[b * 12 + j] = nv;
    __syncthreads();
  }
  float v = al[b * 12 + j] + endt[j];
  __syncthreads();
  al[b * 12 + j] = v;
  __syncthreads();
  if (j == 0) {
    float mx = al[b * 12];
#pragma unroll
    for (int i = 1; i < 9; ++i) mx = fmaxf(mx, al[b * 12 + i]);
    float sm = 0.f;
#pragma unroll
    for (int i = 0; i < 9; ++i) sm += __expf(al[b * 12 + i] - mx);
    denom[b] = mx + __logf(sm);
  }
}

// ---------------------------------------------------------------------------
// K6: out = mean_b(denom - score)
// ---------------------------------------------------------------------------
__global__ void k_final(const float* __restrict__ score,
                        const float* __restrict__ denom, float* __restrict__ out)
{
  int l = threadIdx.x;
  float v = denom[l] - score[l];
#pragma unroll
  for (int off = 32; off; off >>= 1) v += __shfl_down(v, off, 64);
  if (l == 0) out[0] = v * (1.0f / 64.0f);
}

// ---------------------------------------------------------------------------
// Workspace layout (bytes):
//   xproj  bf16 [32768][1024]       : 67,108,864
//   h_glob bf16 [2][512][64][128]   : 16,777,216
//   em     f32  [512][64][9]        :  1,179,648
//   score  f32  [64] (+pad)         :        256
//   denom  f32  [64] (+pad)         :        256
//   chainM f32  [64][64][9][9]      :  1,327,104
// ---------------------------------------------------------------------------
extern "C" void kernel_launch(void* const* d_in, const int* in_sizes, int n_in,
                              void* d_out, int out_size, void* d_ws, size_t ws_size,
                              hipStream_t stream) {
  const int*   words = (const int*)d_in[0];
  const int*   tags  = (const int*)d_in[1];
  const float* emb   = (const float*)d_in[3];
  const float* Wih_f = (const float*)d_in[4];
  const float* Whh_f = (const float*)d_in[5];
  const float* bih_f = (const float*)d_in[6];
  const float* bhh_f = (const float*)d_in[7];
  const float* Wih_b = (const float*)d_in[8];
  const float* Whh_b = (const float*)d_in[9];
  const float* bih_b = (const float*)d_in[10];
  const float* bhh_b = (const float*)d_in[11];
  const float* W_out = (const float*)d_in[12];
  const float* b_out = (const float*)d_in[13];
  const float* st    = (const float*)d_in[14];
  const float* en    = (const float*)d_in[15];
  const float* tr    = (const float*)d_in[16];

  char* ws = (char*)d_ws;
  u16*   xproj  = (u16*)(ws);
  u16*   h_glob = (u16*)(ws + 67108864);
  float* em     = (float*)(ws + 67108864 + 16777216);
  float* score  = (float*)(ws + 67108864 + 16777216 + 1179648);
  float* denom  = (float*)(ws + 67108864 + 16777216 + 1179648 + 256);
  float* chainM = (float*)(ws + 67108864 + 16777216 + 1179648 + 512);

  hipLaunchKernelGGL(k_xproj, dim3(256, 8), dim3(256), 0, stream,
                     words, emb, Wih_f, Wih_b, bih_f, bhh_f, bih_b, bhh_b, xproj);
  hipLaunchKernelGGL(k_lstm, dim3(8), dim3(512), 0, stream,
                     xproj, Whh_f, Whh_b, h_glob);
  hipLaunchKernelGGL(k_em, dim3(128), dim3(256), 0, stream,
                     h_glob, W_out, b_out, em);
  hipLaunchKernelGGL(k_score, dim3(64), dim3(256), 0, stream,
                     tags, em, st, en, tr, score);
  hipLaunchKernelGGL(k_chainA, dim3(256), dim3(256), 0, stream,
                     em, tr, chainM);
  hipLaunchKernelGGL(k_denomB, dim3(1), dim3(576), 0, stream,
                     em, chainM, st, en, denom);
  hipLaunchKernelGGL(k_final, dim3(1), dim3(64), 0, stream,
                     score, denom, (float*)d_out);
}

// Round 3
// 1049.960 us; speedup vs baseline: 1.0183x; 1.0183x over previous
//
#include <hip/hip_runtime.h>
#include <hip/hip_bf16.h>

// Problem constants
#define S_LEN 512
#define BATCH 64
#define EMB   300
#define HD    128
#define G4    512      // 4*HD
#define NT    9
#define NCH   64       // CRF scan chunks
#define CHL   8        // chunk length (last chunk = 7)

typedef unsigned short u16;
typedef __attribute__((ext_vector_type(8))) short short8;
typedef __attribute__((ext_vector_type(4))) float f32x4;

__device__ __forceinline__ float bf2f(u16 u) {
  union { unsigned int i; float f; } v; v.i = ((unsigned int)u) << 16; return v.f;
}
__device__ __forceinline__ u16 f2bf(float f) {
  union { float f; unsigned int i; } v; v.f = f;
  unsigned int u = v.i + 0x7fffu + ((v.i >> 16) & 1u);   // RNE, finite inputs
  return (u16)(u >> 16);
}
__device__ __forceinline__ float sigm(float x) { return 1.0f / (1.0f + __expf(-x)); }
__device__ __forceinline__ float tanh_(float x) {
  float e = __expf(-2.0f * fabsf(x));
  float t = (1.0f - e) / (1.0f + e);
  return x >= 0.0f ? t : -t;
}
__device__ __forceinline__ u16 u4get(ushort4 v, int r) {
  return r == 0 ? v.x : r == 1 ? v.y : r == 2 ? v.z : v.w;
}

// ---------------------------------------------------------------------------
// K1: embedding gather + input projection GEMM (bf16 MFMA).  (unchanged)
// xproj[m][n], m = s*64+b, n in [0,1024): n<512 fwd, else bwd; i,f,g,o blocks.
// ---------------------------------------------------------------------------
__global__ __launch_bounds__(256) void k_xproj(
    const int* __restrict__ words, const float* __restrict__ emb,
    const float* __restrict__ Wf, const float* __restrict__ Wb,
    const float* __restrict__ bihf, const float* __restrict__ bhhf,
    const float* __restrict__ bihb, const float* __restrict__ bhhb,
    u16* __restrict__ xproj)
{
  __shared__ u16  As[128 * 40];
  __shared__ u16  Bs[128 * 40];
  __shared__ int  wlds[128];
  __shared__ float blds[128];
  const int tid = threadIdx.x;
  const int m0 = blockIdx.x * 128;
  const int n0 = blockIdx.y * 128;
  if (tid < 128) {
    int m = m0 + tid;
    wlds[tid] = words[(m & 63) * S_LEN + (m >> 6)];
    int n = n0 + tid;
    blds[tid] = (n < G4) ? (bihf[n] + bhhf[n]) : (bihb[n - G4] + bhhb[n - G4]);
  }
  __syncthreads();

  const int lane = tid & 63;
  const int w = tid >> 6;
  const int wr = w >> 1, wc = w & 1;
  const int l15 = lane & 15, l4 = lane >> 4;

  f32x4 acc[4][4];
#pragma unroll
  for (int a = 0; a < 4; ++a)
#pragma unroll
    for (int b = 0; b < 4; ++b) acc[a][b] = (f32x4){0.f, 0.f, 0.f, 0.f};

  const int rr = tid >> 3;
  const int kk = (tid & 7) * 4;

  for (int kt = 0; kt < 10; ++kt) {
    const int k0 = kt * 32;
    if (kt) __syncthreads();
#pragma unroll
    for (int q = 0; q < 4; ++q) {
      int r = rr + q * 32;
      {
        const float* src = emb + (long)wlds[r] * EMB + (k0 + kk);
        float4 v;
        if (k0 + kk + 3 < EMB) v = *(const float4*)src;
        else {
          v.x = (k0 + kk + 0 < EMB) ? src[0] : 0.f;
          v.y = (k0 + kk + 1 < EMB) ? src[1] : 0.f;
          v.z = (k0 + kk + 2 < EMB) ? src[2] : 0.f;
          v.w = (k0 + kk + 3 < EMB) ? src[3] : 0.f;
        }
        ushort4 o = { f2bf(v.x), f2bf(v.y), f2bf(v.z), f2bf(v.w) };
        *(ushort4*)&As[r * 40 + kk] = o;
      }
      {
        int n = n0 + r;
        const float* src = (n < G4) ? (Wf + (long)n * EMB + (k0 + kk))
                                    : (Wb + (long)(n - G4) * EMB + (k0 + kk));
        float4 v;
        if (k0 + kk + 3 < EMB) v = *(const float4*)src;
        else {
          v.x = (k0 + kk + 0 < EMB) ? src[0] : 0.f;
          v.y = (k0 + kk + 1 < EMB) ? src[1] : 0.f;
          v.z = (k0 + kk + 2 < EMB) ? src[2] : 0.f;
          v.w = (k0 + kk + 3 < EMB) ? src[3] : 0.f;
        }
        ushort4 o = { f2bf(v.x), f2bf(v.y), f2bf(v.z), f2bf(v.w) };
        *(ushort4*)&Bs[r * 40 + kk] = o;
      }
    }
    __syncthreads();

    short8 af[4], bfv[4];
#pragma unroll
    for (int mt = 0; mt < 4; ++mt)
      af[mt] = *(const short8*)&As[(wr * 64 + mt * 16 + l15) * 40 + l4 * 8];
#pragma unroll
    for (int nt = 0; nt < 4; ++nt)
      bfv[nt] = *(const short8*)&Bs[(wc * 64 + nt * 16 + l15) * 40 + l4 * 8];
#pragma unroll
    for (int mt = 0; mt < 4; ++mt)
#pragma unroll
      for (int nt = 0; nt < 4; ++nt)
        acc[mt][nt] = __builtin_amdgcn_mfma_f32_16x16x32_bf16(af[mt], bfv[nt], acc[mt][nt], 0, 0, 0);
  }

#pragma unroll
  for (int nt = 0; nt < 4; ++nt) {
    int col = wc * 64 + nt * 16 + l15;
    float bias = blds[col];
    long n = n0 + col;
#pragma unroll
    for (int mt = 0; mt < 4; ++mt) {
#pragma unroll
      for (int r = 0; r < 4; ++r) {
        int m = m0 + wr * 64 + mt * 16 + l4 * 4 + r;
        xproj[(long)m * 1024 + n] = f2bf(acc[mt][nt][r] + bias);
      }
    }
  }
}

// ---------------------------------------------------------------------------
// K2: LSTM recurrence, gate-register-local + 4-deep prefetch pipeline.
// 8 blocks = 2 dirs x 4 groups of 16 batches, 512 threads (8 waves).
// Wave w owns j in [16w,16w+16) for ALL 4 gates; (i,f,g,o)[j] land in one
// lane's registers. Only h crosses waves (double-buffered swizzled LDS).
// Main loop: raw s_barrier + lgkmcnt(0) only — vmcnt NEVER drained, so the
// 4-step-ahead xproj prefetch stays in flight across barriers.
// ---------------------------------------------------------------------------
#define LSTM_PHASE(P)                                                         \
  {                                                                           \
    const int tcur = t0 + (P);                                                \
    short8 bfr[4];                                                            \
    _Pragma("unroll")                                                         \
    for (int kt = 0; kt < 4; ++kt) {                                          \
      int off = l15 * 256 + ((kt * 64 + l4 * 16) ^ swz);                      \
      bfr[kt] = *(const short8*)((const char*)&hls[(P) & 1][0] + off);        \
    }                                                                         \
    f32x4 a0 = {0.f,0.f,0.f,0.f}, a1 = {0.f,0.f,0.f,0.f};                     \
    f32x4 a2 = {0.f,0.f,0.f,0.f}, a3 = {0.f,0.f,0.f,0.f};                     \
    _Pragma("unroll")                                                         \
    for (int kt = 0; kt < 4; ++kt) {                                          \
      a0 = __builtin_amdgcn_mfma_f32_16x16x32_bf16(afr[0][kt], bfr[kt], a0, 0, 0, 0); \
      a1 = __builtin_amdgcn_mfma_f32_16x16x32_bf16(afr[1][kt], bfr[kt], a1, 0, 0, 0); \
      a2 = __builtin_amdgcn_mfma_f32_16x16x32_bf16(afr[2][kt], bfr[kt], a2, 0, 0, 0); \
      a3 = __builtin_amdgcn_mfma_f32_16x16x32_bf16(afr[3][kt], bfr[kt], a3, 0, 0, 0); \
    }                                                                         \
    float hr[4];                                                              \
    _Pragma("unroll")                                                         \
    for (int r = 0; r < 4; ++r) {                                             \
      float gi = a0[r] + bf2f(u4get(xp[P][0], r));                            \
      float gf = a1[r] + bf2f(u4get(xp[P][1], r));                            \
      float gg = a2[r] + bf2f(u4get(xp[P][2], r));                            \
      float go = a3[r] + bf2f(u4get(xp[P][3], r));                            \
      float si = sigm(gi), sf = sigm(gf), tg = tanh_(gg), so = sigm(go);      \
      c[r] = sf * c[r] + si * tg;                                             \
      hr[r] = so * tanh_(c[r]);                                               \
    }                                                                         \
    ushort4 hv;                                                               \
    hv.x = f2bf(hr[0]); hv.y = f2bf(hr[1]);                                   \
    hv.z = f2bf(hr[2]); hv.w = f2bf(hr[3]);                                   \
    {                                                                         \
      int tn = tcur + 4; tn = tn < S_LEN ? tn : S_LEN - 1;                    \
      int sn = dir ? (S_LEN - 1 - tn) : tn;                                   \
      const long xb = ((long)sn * BATCH + bglob) * 1024 + (long)dir * G4;     \
      _Pragma("unroll")                                                       \
      for (int g = 0; g < 4; ++g)                                             \
        xp[P][g] = *(const ushort4*)&xproj[xb + g * 128 + jbase];             \
    }                                                                         \
    *(ushort4*)((char*)&hls[((P) & 1) ^ 1][0] + l15 * 256 + wbyte) = hv;      \
    {                                                                         \
      int s = dir ? (S_LEN - 1 - tcur) : tcur;                                \
      *(ushort4*)&h_glob[((long)((dir * S_LEN + s) * BATCH + bglob)) * HD + jbase] = hv; \
    }                                                                         \
    __builtin_amdgcn_sched_barrier(0);                                        \
    asm volatile("s_waitcnt lgkmcnt(0)");                                     \
    __builtin_amdgcn_s_barrier();                                             \
    __builtin_amdgcn_sched_barrier(0);                                        \
  }

__global__ __launch_bounds__(512) void k_lstm(
    const u16* __restrict__ xproj, const float* __restrict__ Whh_f,
    const float* __restrict__ Whh_b, u16* __restrict__ h_glob)
{
  __shared__ u16 hls[2][16 * HD];   // [buf][batch row (256B)][swizzled j*2]

  const int dir = blockIdx.x >> 2;
  const int b0  = (blockIdx.x & 3) * 16;
  const float* Whh = dir ? Whh_b : Whh_f;
  const int tid = threadIdx.x;
  const int lane = tid & 63, w = tid >> 6;
  const int l15 = lane & 15, l4 = lane >> 4;
  const int swz = (l15 & 7) << 4;

  // persistent A-fragments: afr[g][kt], rows g*128 + w*16 + l15
  short8 afr[4][4];
#pragma unroll
  for (int g = 0; g < 4; ++g)
#pragma unroll
    for (int kt = 0; kt < 4; ++kt) {
      const float* src = Whh + (long)(g * 128 + w * 16 + l15) * HD + kt * 32 + l4 * 8;
      float4 v0 = *(const float4*)src;
      float4 v1 = *(const float4*)(src + 4);
      short8 f;
      f[0] = (short)f2bf(v0.x); f[1] = (short)f2bf(v0.y);
      f[2] = (short)f2bf(v0.z); f[3] = (short)f2bf(v0.w);
      f[4] = (short)f2bf(v1.x); f[5] = (short)f2bf(v1.y);
      f[6] = (short)f2bf(v1.z); f[7] = (short)f2bf(v1.w);
      afr[g][kt] = f;
    }
  for (int i = tid; i < 16 * HD; i += 512) hls[0][i] = 0;

  const int bglob = b0 + l15;
  const int jbase = w * 16 + l4 * 4;              // this lane's first j
  const int wbyte = (jbase * 2) ^ swz;            // swizzled LDS byte col for h write
  float c[4] = {0.f, 0.f, 0.f, 0.f};

  // prologue: fill 4-deep prefetch pipeline (slots 0..3 = steps 0..3)
  ushort4 xp[4][4];
#pragma unroll
  for (int pt = 0; pt < 4; ++pt) {
    const int sn = dir ? (S_LEN - 1 - pt) : pt;
    const long xb = ((long)sn * BATCH + bglob) * 1024 + (long)dir * G4;
#pragma unroll
    for (int g = 0; g < 4; ++g)
      xp[pt][g] = *(const ushort4*)&xproj[xb + g * 128 + jbase];
  }
  __syncthreads();   // hls[0] zero-init visibility (once; drain here is fine)

  for (int t0 = 0; t0 < S_LEN; t0 += 4) {
    LSTM_PHASE(0)
    LSTM_PHASE(1)
    LSTM_PHASE(2)
    LSTM_PHASE(3)
  }
}

// ---------------------------------------------------------------------------
// K3: em = [h_f|h_b] @ W_out^T + b_out   (unchanged)
// ---------------------------------------------------------------------------
__global__ __launch_bounds__(256) void k_em(
    const u16* __restrict__ h_glob, const float* __restrict__ W_out,
    const float* __restrict__ b_out, float* __restrict__ em)
{
  __shared__ float wl[NT * 256];
  __shared__ float bl[NT];
  const int tid = threadIdx.x;
  for (int i = tid; i < NT * 256; i += 256) wl[i] = W_out[i];
  if (tid < NT) bl[tid] = b_out[tid];
  __syncthreads();

  const int m = blockIdx.x * 256 + tid;
  const u16* hf = h_glob + (long)m * HD;
  const u16* hb = h_glob + (long)(S_LEN * BATCH + m) * HD;
  float acc[NT];
#pragma unroll
  for (int tg = 0; tg < NT; ++tg) acc[tg] = bl[tg];

#pragma unroll
  for (int ch = 0; ch < 16; ++ch) {
    short8 v = *(const short8*)(hf + ch * 8);
    float f[8];
#pragma unroll
    for (int e = 0; e < 8; ++e) f[e] = bf2f((u16)v[e]);
#pragma unroll
    for (int tg = 0; tg < NT; ++tg) {
      const float* wp = &wl[tg * 256 + ch * 8];
      acc[tg] += f[0]*wp[0] + f[1]*wp[1] + f[2]*wp[2] + f[3]*wp[3]
               + f[4]*wp[4] + f[5]*wp[5] + f[6]*wp[6] + f[7]*wp[7];
    }
  }
#pragma unroll
  for (int ch = 0; ch < 16; ++ch) {
    short8 v = *(const short8*)(hb + ch * 8);
    float f[8];
#pragma unroll
    for (int e = 0; e < 8; ++e) f[e] = bf2f((u16)v[e]);
#pragma unroll
    for (int tg = 0; tg < NT; ++tg) {
      const float* wp = &wl[tg * 256 + 128 + ch * 8];
      acc[tg] += f[0]*wp[0] + f[1]*wp[1] + f[2]*wp[2] + f[3]*wp[3]
               + f[4]*wp[4] + f[5]*wp[5] + f[6]*wp[6] + f[7]*wp[7];
    }
  }
  float* dst = em + (long)m * NT;
#pragma unroll
  for (int tg = 0; tg < NT; ++tg) dst[tg] = acc[tg];
}

// ---------------------------------------------------------------------------
// K4: CRF numerator (gold path score).  (unchanged)
// ---------------------------------------------------------------------------
__global__ __launch_bounds__(256) void k_score(
    const int* __restrict__ tags, const float* __restrict__ em,
    const float* __restrict__ start, const float* __restrict__ endt,
    const float* __restrict__ trans, float* __restrict__ score)
{
  __shared__ float red[256];
  const int b = blockIdx.x, tid = threadIdx.x;
  const int* tg = tags + (long)b * S_LEN;
  float p = 0.f;
  for (int t = tid; t < S_LEN; t += 256) {
    int cur = tg[t];
    if (t == 0) p += start[cur] + em[(long)b * NT + cur];
    else        p += trans[tg[t - 1] * NT + cur] + em[(long)(t * BATCH + b) * NT + cur];
  }
  if (tid == 0) p += endt[tg[S_LEN - 1]];
  red[tid] = p;
  __syncthreads();
  for (int stp = 128; stp; stp >>= 1) {
    if (tid < stp) red[tid] += red[tid + stp];
    __syncthreads();
  }
  if (tid == 0) score[b] = red[0];
}

// ---------------------------------------------------------------------------
// K5a: CRF log-semiring chunk transfer matrices (fully parallel). (unchanged)
// ---------------------------------------------------------------------------
__global__ __launch_bounds__(256) void k_chainA(
    const float* __restrict__ em, const float* __restrict__ trans,
    float* __restrict__ chainM)   // [NCH][BATCH][9][9]
{
  const int tid = threadIdx.x;
  const int pair = (blockIdx.x * 256 + tid) >> 4;   // 0..4095
  const int i = tid & 15;
  const int b = pair & 63;
  const int c = pair >> 6;
  if (i >= 9) return;

  float tr[9][9];
#pragma unroll
  for (int k = 0; k < 9; ++k)
#pragma unroll
    for (int j = 0; j < 9; ++j) tr[k][j] = trans[k * 9 + j];

  const int t0 = 1 + c * CHL;
  const int tend = (t0 + CHL < S_LEN) ? (t0 + CHL) : S_LEN;

  float R[9];
#pragma unroll
  for (int j = 0; j < 9; ++j) R[j] = tr[i][j] + em[((long)t0 * BATCH + b) * NT + j];

  for (int t = t0 + 1; t < tend; ++t) {
    float e[9];
#pragma unroll
    for (int j = 0; j < 9; ++j) e[j] = em[((long)t * BATCH + b) * NT + j];
    float Rn[9];
#pragma unroll
    for (int j = 0; j < 9; ++j) {
      float sv[9];
#pragma unroll
      for (int k = 0; k < 9; ++k) sv[k] = R[k] + tr[k][j];
      float mx = sv[0];
#pragma unroll
      for (int k = 1; k < 9; ++k) mx = fmaxf(mx, sv[k]);
      float sm = 0.f;
#pragma unroll
      for (int k = 0; k < 9; ++k) sm += __expf(sv[k] - mx);
      Rn[j] = mx + __logf(sm) + e[j];
    }
#pragma unroll
    for (int j = 0; j < 9; ++j) R[j] = Rn[j];
  }
#pragma unroll
  for (int j = 0; j < 9; ++j)
    chainM[((long)(c * BATCH + b) * 9 + i) * 9 + j] = R[j];
}

// ---------------------------------------------------------------------------
// K5b: sequential combine over 64 chunk matrices. 1 block, 576 thr. (unchanged)
// ---------------------------------------------------------------------------
__global__ __launch_bounds__(576) void k_denomB(
    const float* __restrict__ em, const float* __restrict__ chainM,
    const float* __restrict__ start, const float* __restrict__ endt,
    float* __restrict__ denom)
{
  __shared__ float al[BATCH * 12];
  const int tid = threadIdx.x;
  const int b = tid / NT, j = tid % NT;
  al[b * 12 + j] = start[j] + em[(long)b * NT + j];
  __syncthreads();

  for (int c = 0; c < NCH; ++c) {
    const float* M = chainM + (long)(c * BATCH + b) * 81 + j;
    float sv[9];
#pragma unroll
    for (int i = 0; i < 9; ++i) sv[i] = al[b * 12 + i] + M[i * 9];
    float mx = sv[0];
#pragma unroll
    for (int i = 1; i < 9; ++i) mx = fmaxf(mx, sv[i]);
    float sm = 0.f;
#pragma unroll
    for (int i = 0; i < 9; ++i) sm += __expf(sv[i] - mx);
    float nv = mx + __logf(sm);
    __syncthreads();
    al[b * 12 + j] = nv;
    __syncthreads();
  }
  float v = al[b * 12 + j] + endt[j];
  __syncthreads();
  al[b * 12 + j] = v;
  __syncthreads();
  if (j == 0) {
    float mx = al[b * 12];
#pragma unroll
    for (int i = 1; i < 9; ++i) mx = fmaxf(mx, al[b * 12 + i]);
    float sm = 0.f;
#pragma unroll
    for (int i = 0; i < 9; ++i) sm += __expf(al[b * 12 + i] - mx);
    denom[b] = mx + __logf(sm);
  }
}

// ---------------------------------------------------------------------------
// K6: out = mean_b(denom - score)
// ---------------------------------------------------------------------------
__global__ void k_final(const float* __restrict__ score,
                        const float* __restrict__ denom, float* __restrict__ out)
{
  int l = threadIdx.x;
  float v = denom[l] - score[l];
#pragma unroll
  for (int off = 32; off; off >>= 1) v += __shfl_down(v, off, 64);
  if (l == 0) out[0] = v * (1.0f / 64.0f);
}

// ---------------------------------------------------------------------------
// Workspace layout (bytes):
//   xproj  bf16 [32768][1024]       : 67,108,864
//   h_glob bf16 [2][512][64][128]   : 16,777,216
//   em     f32  [512][64][9]        :  1,179,648
//   score  f32  [64] (+pad)         :        256
//   denom  f32  [64] (+pad)         :        256
//   chainM f32  [64][64][9][9]      :  1,327,104
// ---------------------------------------------------------------------------
extern "C" void kernel_launch(void* const* d_in, const int* in_sizes, int n_in,
                              void* d_out, int out_size, void* d_ws, size_t ws_size,
                              hipStream_t stream) {
  const int*   words = (const int*)d_in[0];
  const int*   tags  = (const int*)d_in[1];
  const float* emb   = (const float*)d_in[3];
  const float* Wih_f = (const float*)d_in[4];
  const float* Whh_f = (const float*)d_in[5];
  const float* bih_f = (const float*)d_in[6];
  const float* bhh_f = (const float*)d_in[7];
  const float* Wih_b = (const float*)d_in[8];
  const float* Whh_b = (const float*)d_in[9];
  const float* bih_b = (const float*)d_in[10];
  const float* bhh_b = (const float*)d_in[11];
  const float* W_out = (const float*)d_in[12];
  const float* b_out = (const float*)d_in[13];
  const float* st    = (const float*)d_in[14];
  const float* en    = (const float*)d_in[15];
  const float* tr    = (const float*)d_in[16];

  char* ws = (char*)d_ws;
  u16*   xproj  = (u16*)(ws);
  u16*   h_glob = (u16*)(ws + 67108864);
  float* em     = (float*)(ws + 67108864 + 16777216);
  float* score  = (float*)(ws + 67108864 + 16777216 + 1179648);
  float* denom  = (float*)(ws + 67108864 + 16777216 + 1179648 + 256);
  float* chainM = (float*)(ws + 67108864 + 16777216 + 1179648 + 512);

  hipLaunchKernelGGL(k_xproj, dim3(256, 8), dim3(256), 0, stream,
                     words, emb, Wih_f, Wih_b, bih_f, bhh_f, bih_b, bhh_b, xproj);
  hipLaunchKernelGGL(k_lstm, dim3(8), dim3(512), 0, stream,
                     xproj, Whh_f, Whh_b, h_glob);
  hipLaunchKernelGGL(k_em, dim3(128), dim3(256), 0, stream,
                     h_glob, W_out, b_out, em);
  hipLaunchKernelGGL(k_score, dim3(64), dim3(256), 0, stream,
                     tags, em, st, en, tr, score);
  hipLaunchKernelGGL(k_chainA, dim3(256), dim3(256), 0, stream,
                     em, tr, chainM);
  hipLaunchKernelGGL(k_denomB, dim3(1), dim3(576), 0, stream,
                     em, chainM, st, en, denom);
  hipLaunchKernelGGL(k_final, dim3(1), dim3(64), 0, stream,
                     score, denom, (float*)d_out);
}

// Round 4
// 644.194 us; speedup vs baseline: 1.6597x; 1.6299x over previous
//
#include <hip/hip_runtime.h>
#include <hip/hip_bf16.h>

// Problem constants
#define S_LEN 512
#define BATCH 64
#define EMB   300
#define HD    128
#define G4    512      // 4*HD
#define NT    9
#define NCH   64       // CRF scan chunks
#define CHL   8        // chunk length (last chunk = 7)

typedef unsigned short u16;
typedef __attribute__((ext_vector_type(8))) short short8;
typedef __attribute__((ext_vector_type(4))) float f32x4;

__device__ __forceinline__ float bf2f(u16 u) {
  union { unsigned int i; float f; } v; v.i = ((unsigned int)u) << 16; return v.f;
}
__device__ __forceinline__ u16 f2bf(float f) {
  union { float f; unsigned int i; } v; v.f = f;
  unsigned int u = v.i + 0x7fffu + ((v.i >> 16) & 1u);   // RNE, finite inputs
  return (u16)(u >> 16);
}
__device__ __forceinline__ float sigm(float x) { return 1.0f / (1.0f + __expf(-x)); }
__device__ __forceinline__ float tanh_(float x) {
  float e = __expf(-2.0f * fabsf(x));
  float t = (1.0f - e) / (1.0f + e);
  return x >= 0.0f ? t : -t;
}

// ---------------------------------------------------------------------------
// K1: embedding gather + input projection GEMM (bf16 MFMA).  (unchanged)
// xproj[m][n], m = s*64+b, n in [0,1024): n<512 fwd, else bwd; i,f,g,o blocks.
// ---------------------------------------------------------------------------
__global__ __launch_bounds__(256) void k_xproj(
    const int* __restrict__ words, const float* __restrict__ emb,
    const float* __restrict__ Wf, const float* __restrict__ Wb,
    const float* __restrict__ bihf, const float* __restrict__ bhhf,
    const float* __restrict__ bihb, const float* __restrict__ bhhb,
    u16* __restrict__ xproj)
{
  __shared__ u16  As[128 * 40];
  __shared__ u16  Bs[128 * 40];
  __shared__ int  wlds[128];
  __shared__ float blds[128];
  const int tid = threadIdx.x;
  const int m0 = blockIdx.x * 128;
  const int n0 = blockIdx.y * 128;
  if (tid < 128) {
    int m = m0 + tid;
    wlds[tid] = words[(m & 63) * S_LEN + (m >> 6)];
    int n = n0 + tid;
    blds[tid] = (n < G4) ? (bihf[n] + bhhf[n]) : (bihb[n - G4] + bhhb[n - G4]);
  }
  __syncthreads();

  const int lane = tid & 63;
  const int w = tid >> 6;
  const int wr = w >> 1, wc = w & 1;
  const int l15 = lane & 15, l4 = lane >> 4;

  f32x4 acc[4][4];
#pragma unroll
  for (int a = 0; a < 4; ++a)
#pragma unroll
    for (int b = 0; b < 4; ++b) acc[a][b] = (f32x4){0.f, 0.f, 0.f, 0.f};

  const int rr = tid >> 3;
  const int kk = (tid & 7) * 4;

  for (int kt = 0; kt < 10; ++kt) {
    const int k0 = kt * 32;
    if (kt) __syncthreads();
#pragma unroll
    for (int q = 0; q < 4; ++q) {
      int r = rr + q * 32;
      {
        const float* src = emb + (long)wlds[r] * EMB + (k0 + kk);
        float4 v;
        if (k0 + kk + 3 < EMB) v = *(const float4*)src;
        else {
          v.x = (k0 + kk + 0 < EMB) ? src[0] : 0.f;
          v.y = (k0 + kk + 1 < EMB) ? src[1] : 0.f;
          v.z = (k0 + kk + 2 < EMB) ? src[2] : 0.f;
          v.w = (k0 + kk + 3 < EMB) ? src[3] : 0.f;
        }
        ushort4 o = { f2bf(v.x), f2bf(v.y), f2bf(v.z), f2bf(v.w) };
        *(ushort4*)&As[r * 40 + kk] = o;
      }
      {
        int n = n0 + r;
        const float* src = (n < G4) ? (Wf + (long)n * EMB + (k0 + kk))
                                    : (Wb + (long)(n - G4) * EMB + (k0 + kk));
        float4 v;
        if (k0 + kk + 3 < EMB) v = *(const float4*)src;
        else {
          v.x = (k0 + kk + 0 < EMB) ? src[0] : 0.f;
          v.y = (k0 + kk + 1 < EMB) ? src[1] : 0.f;
          v.z = (k0 + kk + 2 < EMB) ? src[2] : 0.f;
          v.w = (k0 + kk + 3 < EMB) ? src[3] : 0.f;
        }
        ushort4 o = { f2bf(v.x), f2bf(v.y), f2bf(v.z), f2bf(v.w) };
        *(ushort4*)&Bs[r * 40 + kk] = o;
      }
    }
    __syncthreads();

    short8 af[4], bfv[4];
#pragma unroll
    for (int mt = 0; mt < 4; ++mt)
      af[mt] = *(const short8*)&As[(wr * 64 + mt * 16 + l15) * 40 + l4 * 8];
#pragma unroll
    for (int nt = 0; nt < 4; ++nt)
      bfv[nt] = *(const short8*)&Bs[(wc * 64 + nt * 16 + l15) * 40 + l4 * 8];
#pragma unroll
    for (int mt = 0; mt < 4; ++mt)
#pragma unroll
      for (int nt = 0; nt < 4; ++nt)
        acc[mt][nt] = __builtin_amdgcn_mfma_f32_16x16x32_bf16(af[mt], bfv[nt], acc[mt][nt], 0, 0, 0);
  }

#pragma unroll
  for (int nt = 0; nt < 4; ++nt) {
    int col = wc * 64 + nt * 16 + l15;
    float bias = blds[col];
    long n = n0 + col;
#pragma unroll
    for (int mt = 0; mt < 4; ++mt) {
#pragma unroll
      for (int r = 0; r < 4; ++r) {
        int m = m0 + wr * 64 + mt * 16 + l4 * 4 + r;
        xproj[(long)m * 1024 + n] = f2bf(acc[mt][nt][r] + bias);
      }
    }
  }
}

// ---------------------------------------------------------------------------
// K2: LSTM recurrence — dense-lane activation via in-wave ds_bpermute.
// 32 blocks = 2 dirs x 16 groups of 4 batches, 512 threads (8 waves).
// Wave w owns j in [16w,16w+16). MFMA roles: lane = (l15=batch-col, l4);
//   D-frag acc[g][r]: gate g, j = 16w + l4*4 + r, batch = l15 (real < 4;
//   B cols 4..15 read zero rows -> acc there is 0, harmless).
// Dense roles: lane y = (jloc = y>>2, bloc = y&3); bpermute transpose pulls
//   all 4 gates of (jloc,bloc) into lane y -> 1 activation element per lane.
// 1 barrier/step; vmcnt never drained; 4-deep xp prefetch.
// ---------------------------------------------------------------------------
#define LSTM_PHASE(P)                                                         \
  {                                                                           \
    const int tcur = t0 + (P);                                                \
    short8 bfr[4];                                                            \
    _Pragma("unroll")                                                         \
    for (int kt = 0; kt < 4; ++kt) {                                          \
      int off = l15 * 256 + ((kt * 64 + l4 * 16) ^ rswz);                     \
      bfr[kt] = *(const short8*)((const char*)&hls[(P) & 1][0] + off);        \
    }                                                                         \
    f32x4 ag[4];                                                              \
    _Pragma("unroll")                                                         \
    for (int g = 0; g < 4; ++g) ag[g] = (f32x4){0.f, 0.f, 0.f, 0.f};          \
    _Pragma("unroll")                                                         \
    for (int kt = 0; kt < 4; ++kt) {                                          \
      ag[0] = __builtin_amdgcn_mfma_f32_16x16x32_bf16(afr[0][kt], bfr[kt], ag[0], 0, 0, 0); \
      ag[1] = __builtin_amdgcn_mfma_f32_16x16x32_bf16(afr[1][kt], bfr[kt], ag[1], 0, 0, 0); \
      ag[2] = __builtin_amdgcn_mfma_f32_16x16x32_bf16(afr[2][kt], bfr[kt], ag[2], 0, 0, 0); \
      ag[3] = __builtin_amdgcn_mfma_f32_16x16x32_bf16(afr[3][kt], bfr[kt], ag[3], 0, 0, 0); \
    }                                                                         \
    float pg[4];                                                              \
    _Pragma("unroll")                                                         \
    for (int g = 0; g < 4; ++g) {                                             \
      int q0 = __builtin_amdgcn_ds_bpermute(bidx, __float_as_int(ag[g][0])); \
      int q1 = __builtin_amdgcn_ds_bpermute(bidx, __float_as_int(ag[g][1])); \
      int q2 = __builtin_amdgcn_ds_bpermute(bidx, __float_as_int(ag[g][2])); \
      int q3 = __builtin_amdgcn_ds_bpermute(bidx, __float_as_int(ag[g][3])); \
      int s01 = selb0 ? q1 : q0;                                              \
      int s23 = selb0 ? q3 : q2;                                              \
      pg[g] = __int_as_float(selb1 ? s23 : s01);                              \
    }                                                                         \
    float gi = pg[0] + bf2f(xp[P].x);                                         \
    float gf = pg[1] + bf2f(xp[P].y);                                         \
    float gg = pg[2] + bf2f(xp[P].z);                                         \
    float go = pg[3] + bf2f(xp[P].w);                                         \
    float si = sigm(gi), sf = sigm(gf), tg = tanh_(gg), so = sigm(go);        \
    c = sf * c + si * tg;                                                     \
    float h = so * tanh_(c);                                                  \
    u16 hb = f2bf(h);                                                         \
    *(u16*)((char*)&hls[((P) & 1) ^ 1][0] + ldswb) = hb;                      \
    {                                                                         \
      int s = dir ? (S_LEN - 1 - tcur) : tcur;                                \
      h_glob[((long)((dir * S_LEN + s) * BATCH + bglob)) * HD + jfull] = hb;  \
    }                                                                         \
    {                                                                         \
      int tn = tcur + 4; tn = tn < S_LEN ? tn : S_LEN - 1;                    \
      int sn = dir ? (S_LEN - 1 - tn) : tn;                                   \
      const u16* xq = xproj + ((long)sn * BATCH + bglob) * 1024 + dir * G4 + jfull; \
      xp[P].x = xq[0]; xp[P].y = xq[128]; xp[P].z = xq[256]; xp[P].w = xq[384]; \
    }                                                                         \
    __builtin_amdgcn_sched_barrier(0);                                        \
    asm volatile("s_waitcnt lgkmcnt(0)");                                     \
    __builtin_amdgcn_s_barrier();                                             \
    __builtin_amdgcn_sched_barrier(0);                                        \
  }

__global__ __launch_bounds__(512) void k_lstm(
    const u16* __restrict__ xproj, const float* __restrict__ Whh_f,
    const float* __restrict__ Whh_b, u16* __restrict__ h_glob)
{
  __shared__ u16 hls[2][16 * HD];   // [buf][row=batch-col (256B)][swizzled j*2]

  const int dir = blockIdx.x >> 4;
  const int b0  = (blockIdx.x & 15) * 4;
  const float* Whh = dir ? Whh_b : Whh_f;
  const int tid = threadIdx.x;
  const int lane = tid & 63, w = tid >> 6;
  const int l15 = lane & 15, l4 = lane >> 4;
  const int rswz = (l15 & 7) << 4;

  // dense roles
  const int jloc = lane >> 2;            // 0..15
  const int bloc = lane & 3;             // 0..3
  const int jfull = w * 16 + jloc;
  const int bglob = b0 + bloc;
  const int bidx = (((jloc >> 2) * 16) + bloc) * 4;   // bpermute byte index
  const bool selb0 = (jloc & 1) != 0;
  const bool selb1 = (jloc & 2) != 0;
  const int ldswb = bloc * 256 + ((2 * jfull) ^ (bloc << 4));

  // persistent A-fragments: afr[g][kt], rows g*128 + w*16 + l15
  short8 afr[4][4];
#pragma unroll
  for (int g = 0; g < 4; ++g)
#pragma unroll
    for (int kt = 0; kt < 4; ++kt) {
      const float* src = Whh + (long)(g * 128 + w * 16 + l15) * HD + kt * 32 + l4 * 8;
      float4 v0 = *(const float4*)src;
      float4 v1 = *(const float4*)(src + 4);
      short8 f;
      f[0] = (short)f2bf(v0.x); f[1] = (short)f2bf(v0.y);
      f[2] = (short)f2bf(v0.z); f[3] = (short)f2bf(v0.w);
      f[4] = (short)f2bf(v1.x); f[5] = (short)f2bf(v1.y);
      f[6] = (short)f2bf(v1.z); f[7] = (short)f2bf(v1.w);
      afr[g][kt] = f;
    }
  for (int i = tid; i < 2 * 16 * HD; i += 512) ((u16*)hls)[i] = 0;

  float c = 0.f;

  // prologue: fill 4-deep prefetch pipeline (slots 0..3 = steps 0..3)
  ushort4 xp[4];
#pragma unroll
  for (int pt = 0; pt < 4; ++pt) {
    const int sn = dir ? (S_LEN - 1 - pt) : pt;
    const u16* xq = xproj + ((long)sn * BATCH + bglob) * 1024 + dir * G4 + jfull;
    xp[pt].x = xq[0]; xp[pt].y = xq[128]; xp[pt].z = xq[256]; xp[pt].w = xq[384];
  }
  __syncthreads();   // hls zero-init visibility (once; drain here is fine)

  for (int t0 = 0; t0 < S_LEN; t0 += 4) {
    LSTM_PHASE(0)
    LSTM_PHASE(1)
    LSTM_PHASE(2)
    LSTM_PHASE(3)
  }
}

// ---------------------------------------------------------------------------
// K3: em = [h_f|h_b] @ W_out^T + b_out   (unchanged)
// ---------------------------------------------------------------------------
__global__ __launch_bounds__(256) void k_em(
    const u16* __restrict__ h_glob, const float* __restrict__ W_out,
    const float* __restrict__ b_out, float* __restrict__ em)
{
  __shared__ float wl[NT * 256];
  __shared__ float bl[NT];
  const int tid = threadIdx.x;
  for (int i = tid; i < NT * 256; i += 256) wl[i] = W_out[i];
  if (tid < NT) bl[tid] = b_out[tid];
  __syncthreads();

  const int m = blockIdx.x * 256 + tid;
  const u16* hf = h_glob + (long)m * HD;
  const u16* hb = h_glob + (long)(S_LEN * BATCH + m) * HD;
  float acc[NT];
#pragma unroll
  for (int tg = 0; tg < NT; ++tg) acc[tg] = bl[tg];

#pragma unroll
  for (int ch = 0; ch < 16; ++ch) {
    short8 v = *(const short8*)(hf + ch * 8);
    float f[8];
#pragma unroll
    for (int e = 0; e < 8; ++e) f[e] = bf2f((u16)v[e]);
#pragma unroll
    for (int tg = 0; tg < NT; ++tg) {
      const float* wp = &wl[tg * 256 + ch * 8];
      acc[tg] += f[0]*wp[0] + f[1]*wp[1] + f[2]*wp[2] + f[3]*wp[3]
               + f[4]*wp[4] + f[5]*wp[5] + f[6]*wp[6] + f[7]*wp[7];
    }
  }
#pragma unroll
  for (int ch = 0; ch < 16; ++ch) {
    short8 v = *(const short8*)(hb + ch * 8);
    float f[8];
#pragma unroll
    for (int e = 0; e < 8; ++e) f[e] = bf2f((u16)v[e]);
#pragma unroll
    for (int tg = 0; tg < NT; ++tg) {
      const float* wp = &wl[tg * 256 + 128 + ch * 8];
      acc[tg] += f[0]*wp[0] + f[1]*wp[1] + f[2]*wp[2] + f[3]*wp[3]
               + f[4]*wp[4] + f[5]*wp[5] + f[6]*wp[6] + f[7]*wp[7];
    }
  }
  float* dst = em + (long)m * NT;
#pragma unroll
  for (int tg = 0; tg < NT; ++tg) dst[tg] = acc[tg];
}

// ---------------------------------------------------------------------------
// K4: CRF numerator (gold path score).  (unchanged)
// ---------------------------------------------------------------------------
__global__ __launch_bounds__(256) void k_score(
    const int* __restrict__ tags, const float* __restrict__ em,
    const float* __restrict__ start, const float* __restrict__ endt,
    const float* __restrict__ trans, float* __restrict__ score)
{
  __shared__ float red[256];
  const int b = blockIdx.x, tid = threadIdx.x;
  const int* tg = tags + (long)b * S_LEN;
  float p = 0.f;
  for (int t = tid; t < S_LEN; t += 256) {
    int cur = tg[t];
    if (t == 0) p += start[cur] + em[(long)b * NT + cur];
    else        p += trans[tg[t - 1] * NT + cur] + em[(long)(t * BATCH + b) * NT + cur];
  }
  if (tid == 0) p += endt[tg[S_LEN - 1]];
  red[tid] = p;
  __syncthreads();
  for (int stp = 128; stp; stp >>= 1) {
    if (tid < stp) red[tid] += red[tid + stp];
    __syncthreads();
  }
  if (tid == 0) score[b] = red[0];
}

// ---------------------------------------------------------------------------
// K5a: CRF log-semiring chunk transfer matrices (fully parallel). (unchanged)
// ---------------------------------------------------------------------------
__global__ __launch_bounds__(256) void k_chainA(
    const float* __restrict__ em, const float* __restrict__ trans,
    float* __restrict__ chainM)   // [NCH][BATCH][9][9]
{
  const int tid = threadIdx.x;
  const int pair = (blockIdx.x * 256 + tid) >> 4;   // 0..4095
  const int i = tid & 15;
  const int b = pair & 63;
  const int c = pair >> 6;
  if (i >= 9) return;

  float tr[9][9];
#pragma unroll
  for (int k = 0; k < 9; ++k)
#pragma unroll
    for (int j = 0; j < 9; ++j) tr[k][j] = trans[k * 9 + j];

  const int t0 = 1 + c * CHL;
  const int tend = (t0 + CHL < S_LEN) ? (t0 + CHL) : S_LEN;

  float R[9];
#pragma unroll
  for (int j = 0; j < 9; ++j) R[j] = tr[i][j] + em[((long)t0 * BATCH + b) * NT + j];

  for (int t = t0 + 1; t < tend; ++t) {
    float e[9];
#pragma unroll
    for (int j = 0; j < 9; ++j) e[j] = em[((long)t * BATCH + b) * NT + j];
    float Rn[9];
#pragma unroll
    for (int j = 0; j < 9; ++j) {
      float sv[9];
#pragma unroll
      for (int k = 0; k < 9; ++k) sv[k] = R[k] + tr[k][j];
      float mx = sv[0];
#pragma unroll
      for (int k = 1; k < 9; ++k) mx = fmaxf(mx, sv[k]);
      float sm = 0.f;
#pragma unroll
      for (int k = 0; k < 9; ++k) sm += __expf(sv[k] - mx);
      Rn[j] = mx + __logf(sm) + e[j];
    }
#pragma unroll
    for (int j = 0; j < 9; ++j) R[j] = Rn[j];
  }
#pragma unroll
  for (int j = 0; j < 9; ++j)
    chainM[((long)(c * BATCH + b) * 9 + i) * 9 + j] = R[j];
}

// ---------------------------------------------------------------------------
// K5b: sequential combine over 64 chunk matrices. 1 block, 576 thr. (unchanged)
// ---------------------------------------------------------------------------
__global__ __launch_bounds__(576) void k_denomB(
    const float* __restrict__ em, const float* __restrict__ chainM,
    const float* __restrict__ start, const float* __restrict__ endt,
    float* __restrict__ denom)
{
  __shared__ float al[BATCH * 12];
  const int tid = threadIdx.x;
  const int b = tid / NT, j = tid % NT;
  al[b * 12 + j] = start[j] + em[(long)b * NT + j];
  __syncthreads();

  for (int c = 0; c < NCH; ++c) {
    const float* M = chainM + (long)(c * BATCH + b) * 81 + j;
    float sv[9];
#pragma unroll
    for (int i = 0; i < 9; ++i) sv[i] = al[b * 12 + i] + M[i * 9];
    float mx = sv[0];
#pragma unroll
    for (int i = 1; i < 9; ++i) mx = fmaxf(mx, sv[i]);
    float sm = 0.f;
#pragma unroll
    for (int i = 0; i < 9; ++i) sm += __expf(sv[i] - mx);
    float nv = mx + __logf(sm);
    __syncthreads();
    al[b * 12 + j] = nv;
    __syncthreads();
  }
  float v = al[b * 12 + j] + endt[j];
  __syncthreads();
  al[b * 12 + j] = v;
  __syncthreads();
  if (j == 0) {
    float mx = al[b * 12];
#pragma unroll
    for (int i = 1; i < 9; ++i) mx = fmaxf(mx, al[b * 12 + i]);
    float sm = 0.f;
#pragma unroll
    for (int i = 0; i < 9; ++i) sm += __expf(al[b * 12 + i] - mx);
    denom[b] = mx + __logf(sm);
  }
}

// ---------------------------------------------------------------------------
// K6: out = mean_b(denom - score)
// ---------------------------------------------------------------------------
__global__ void k_final(const float* __restrict__ score,
                        const float* __restrict__ denom, float* __restrict__ out)
{
  int l = threadIdx.x;
  float v = denom[l] - score[l];
#pragma unroll
  for (int off = 32; off; off >>= 1) v += __shfl_down(v, off, 64);
  if (l == 0) out[0] = v * (1.0f / 64.0f);
}

// ---------------------------------------------------------------------------
// Workspace layout (bytes):
//   xproj  bf16 [32768][1024]       : 67,108,864
//   h_glob bf16 [2][512][64][128]   : 16,777,216
//   em     f32  [512][64][9]        :  1,179,648
//   score  f32  [64] (+pad)         :        256
//   denom  f32  [64] (+pad)         :        256
//   chainM f32  [64][64][9][9]      :  1,327,104
// ---------------------------------------------------------------------------
extern "C" void kernel_launch(void* const* d_in, const int* in_sizes, int n_in,
                              void* d_out, int out_size, void* d_ws, size_t ws_size,
                              hipStream_t stream) {
  const int*   words = (const int*)d_in[0];
  const int*   tags  = (const int*)d_in[1];
  const float* emb   = (const float*)d_in[3];
  const float* Wih_f = (const float*)d_in[4];
  const float* Whh_f = (const float*)d_in[5];
  const float* bih_f = (const float*)d_in[6];
  const float* bhh_f = (const float*)d_in[7];
  const float* Wih_b = (const float*)d_in[8];
  const float* Whh_b = (const float*)d_in[9];
  const float* bih_b = (const float*)d_in[10];
  const float* bhh_b = (const float*)d_in[11];
  const float* W_out = (const float*)d_in[12];
  const float* b_out = (const float*)d_in[13];
  const float* st    = (const float*)d_in[14];
  const float* en    = (const float*)d_in[15];
  const float* tr    = (const float*)d_in[16];

  char* ws = (char*)d_ws;
  u16*   xproj  = (u16*)(ws);
  u16*   h_glob = (u16*)(ws + 67108864);
  float* em     = (float*)(ws + 67108864 + 16777216);
  float* score  = (float*)(ws + 67108864 + 16777216 + 1179648);
  float* denom  = (float*)(ws + 67108864 + 16777216 + 1179648 + 256);
  float* chainM = (float*)(ws + 67108864 + 16777216 + 1179648 + 512);

  hipLaunchKernelGGL(k_xproj, dim3(256, 8), dim3(256), 0, stream,
                     words, emb, Wih_f, Wih_b, bih_f, bhh_f, bih_b, bhh_b, xproj);
  hipLaunchKernelGGL(k_lstm, dim3(32), dim3(512), 0, stream,
                     xproj, Whh_f, Whh_b, h_glob);
  hipLaunchKernelGGL(k_em, dim3(128), dim3(256), 0, stream,
                     h_glob, W_out, b_out, em);
  hipLaunchKernelGGL(k_score, dim3(64), dim3(256), 0, stream,
                     tags, em, st, en, tr, score);
  hipLaunchKernelGGL(k_chainA, dim3(256), dim3(256), 0, stream,
                     em, tr, chainM);
  hipLaunchKernelGGL(k_denomB, dim3(1), dim3(576), 0, stream,
                     em, chainM, st, en, denom);
  hipLaunchKernelGGL(k_final, dim3(1), dim3(64), 0, stream,
                     score, denom, (float*)d_out);
}